// Round 4
// baseline (35829.663 us; speedup 1.0000x reference)
//
#include <hip/hip_runtime.h>
#include <math.h>

// resRNN fwd: N=256 seqs, L=1024 steps, inp=521 (8 x + 1 storage + 512 hx),
// HID=512, OUT=1, fp32 (no fp32 MFMA on CDNA4; low-precision weights blow the
// error budget given the recurrence's error amplification).
//
// Round 4 = round 3 with the ds_swizzle pattern as a template arg (the builtin
// requires an integer-constant-expression BEFORE inlining; a const param fails
// sema). Design recap: 128 blocks x 512 threads, 2 batch/block. K-sliced
// matvec: thread t = (jg=t>>3, p=t&7) owns cols [8jg,8jg+8) over rows
// [65p, 65p+65] (inp stored as 8 slices padded to 68 floats, pads = 0 so the
// +1 overlap row contributes 0 -> uniform, branch-free).
//   rows 0..15  of slice: VGPR-resident weights (32 float4 = 128 regs)
//   rows 16..63: streamed from L2 as float4s, explicit A/B double buffer
//   rows 64..65: LDS-resident (32 KB, lane-stride-1 banks)
// Cross-slice reduce: quad_perm DPP (xor1,xor2) + ds_swizzle (xor4).

constexpr int kN   = 256;
constexpr int kL   = 1024;
constexpr int kHid = 512;
constexpr int kBlk = 512;
constexpr int kBpb = 2;
constexpr int PADSL = 68;              // padded slice stride (floats), 16B-aligned

template <int CTRL>
__device__ __forceinline__ float dpp_xor_add(float x) {
  int yi = __builtin_amdgcn_update_dpp(0, __float_as_int(x), CTRL, 0xF, 0xF, true);
  return x + __int_as_float(yi);
}
template <int PAT>
__device__ __forceinline__ float swz_add(float x) {
  int yi = __builtin_amdgcn_ds_swizzle(__float_as_int(x), PAT);
  return x + __int_as_float(yi);
}

__global__ __launch_bounds__(kBlk, 2)
void resrnn_fwd(const float* __restrict__ x, const float* __restrict__ W1,
                const float* __restrict__ b1, const float* __restrict__ W2,
                const float* __restrict__ b2, float* __restrict__ out) {
  __shared__ float wlds[16 * kBlk];                    // rows {64,65} x 8 cols, 32 KB
  __shared__ __align__(16) float in0[8 * PADSL];       // 544 floats
  __shared__ __align__(16) float in1[8 * PADSL];
  __shared__ float red[2][8];

  const int t_  = threadIdx.x;
  const int p   = t_ & 7;        // k-slice
  const int col0 = t_ & ~7;      // = 8*(t_>>3), col-octet base
  const int kbase = 65 * p;      // slice start row

  const int n0 = blockIdx.x * kBpb;
  const int n1 = n0 + 1;
  const float* __restrict__ x0 = x + (size_t)n0 * kL * 8;
  const float* __restrict__ x1 = x + (size_t)n1 * kL * 8;
  float* const outp = out;
  float* const stor = out + (size_t)kN * kL;

  const float b2v = b2[0];
  const float b1t = b1[t_];
  const float w2t = W2[t_];

  const float* __restrict__ wbase = W1 + (size_t)kbase * kHid + col0;

  // ---- weight residency preload ----
  float4 wr[16][2];
  #pragma unroll
  for (int r = 0; r < 16; ++r) {
    wr[r][0] = *reinterpret_cast<const float4*>(wbase + r * kHid);
    wr[r][1] = *reinterpret_cast<const float4*>(wbase + r * kHid + 4);
  }
  #pragma unroll
  for (int r = 0; r < 2; ++r)
    #pragma unroll
    for (int c = 0; c < 8; ++c)
      wlds[(r * 8 + c) * kBlk + t_] = wbase[(64 + r) * kHid + c];
  const float* __restrict__ wst = wbase + 16 * kHid;   // streamed rows 16..63

  // ---- staging address for hidden row 9+t_ (slice layout) ----
  const int R = 9 + t_;
  const int haddr = (R < 455) ? (R / 65) * PADSL + (R % 65)
                              : 7 * PADSL + (R - 455);

  // ---- init: zero inp (incl. pads), then stage x_0 / s_0 ----
  in0[t_] = 0.f; in1[t_] = 0.f;
  if (t_ < 8 * PADSL - kBlk) { in0[kBlk + t_] = 0.f; in1[kBlk + t_] = 0.f; }
  __syncthreads();
  float s0 = x0[0];
  float s1 = x1[0];
  if (t_ < 8)       in0[t_]     = x0[t_];
  else if (t_ < 16) in1[t_ - 8] = x1[t_ - 8];
  if (t_ == 16)     in0[8] = s0;
  if (t_ == 17)     in1[8] = s1;
  if (t_ == 0) { stor[n0 * kL] = s0; stor[n1 * kL] = s1; }
  __syncthreads();

  const float4* __restrict__ in0f4 = reinterpret_cast<const float4*>(in0 + p * PADSL);
  const float4* __restrict__ in1f4 = reinterpret_cast<const float4*>(in1 + p * PADSL);
  const float* __restrict__ sin0 = in0 + p * PADSL;
  const float* __restrict__ sin1 = in1 + p * PADSL;

  float acc[8][2];
  float4 bufA[4], bufB[4];

  auto load2 = [&](float4* buf, int hc) {            // 2 rows: 16+2hc, 17+2hc
    const float* b = wst + hc * 2 * kHid;
    buf[0] = *reinterpret_cast<const float4*>(b);
    buf[1] = *reinterpret_cast<const float4*>(b + 4);
    buf[2] = *reinterpret_cast<const float4*>(b + kHid);
    buf[3] = *reinterpret_cast<const float4*>(b + kHid + 4);
  };
  auto fmarow = [&](float ia, float ib, const float4& w0, const float4& w1) {
    acc[0][0] = fmaf(ia, w0.x, acc[0][0]);  acc[0][1] = fmaf(ib, w0.x, acc[0][1]);
    acc[1][0] = fmaf(ia, w0.y, acc[1][0]);  acc[1][1] = fmaf(ib, w0.y, acc[1][1]);
    acc[2][0] = fmaf(ia, w0.z, acc[2][0]);  acc[2][1] = fmaf(ib, w0.z, acc[2][1]);
    acc[3][0] = fmaf(ia, w0.w, acc[3][0]);  acc[3][1] = fmaf(ib, w0.w, acc[3][1]);
    acc[4][0] = fmaf(ia, w1.x, acc[4][0]);  acc[4][1] = fmaf(ib, w1.x, acc[4][1]);
    acc[5][0] = fmaf(ia, w1.y, acc[5][0]);  acc[5][1] = fmaf(ib, w1.y, acc[5][1]);
    acc[6][0] = fmaf(ia, w1.z, acc[6][0]);  acc[6][1] = fmaf(ib, w1.z, acc[6][1]);
    acc[7][0] = fmaf(ia, w1.w, acc[7][0]);  acc[7][1] = fmaf(ib, w1.w, acc[7][1]);
  };

  for (int t = 0; t < kL; ++t) {
    // ---- prefetch x(t+1): consumed at staging time (latency hidden) ----
    float xs0 = 0.f, xs1 = 0.f, xnext = 0.f;
    if (t + 1 < kL) {
      const float* xr0 = x0 + (size_t)(t + 1) * 8;
      const float* xr1 = x1 + (size_t)(t + 1) * 8;
      xs0 = xr0[0];  xs1 = xr1[0];
      if (t_ < 8)       xnext = xr0[t_];
      else if (t_ < 16) xnext = xr1[t_ - 8];
    }

    #pragma unroll
    for (int c = 0; c < 8; ++c) { acc[c][0] = 0.f; acc[c][1] = 0.f; }

    load2(bufA, 0);  // kick stream early

    // ---- VGPR-resident rows 0..15 (inp f4 groups 0..3) ----
    #pragma unroll
    for (int i = 0; i < 4; ++i) {
      const float4 va = in0f4[i];
      const float4 vb = in1f4[i];
      fmarow(va.x, vb.x, wr[4 * i + 0][0], wr[4 * i + 0][1]);
      fmarow(va.y, vb.y, wr[4 * i + 1][0], wr[4 * i + 1][1]);
      fmarow(va.z, vb.z, wr[4 * i + 2][0], wr[4 * i + 2][1]);
      fmarow(va.w, vb.w, wr[4 * i + 3][0], wr[4 * i + 3][1]);
    }

    // ---- streamed rows 16..63: 12 f4-groups, A/B half-chunk pipeline ----
    for (int jj = 0; jj < 12; ++jj) {
      load2(bufB, 2 * jj + 1);
      const float4 va = in0f4[4 + jj];
      const float4 vb = in1f4[4 + jj];
      fmarow(va.x, vb.x, bufA[0], bufA[1]);   // row 16+4jj   (from A = hc 2jj)
      fmarow(va.y, vb.y, bufA[2], bufA[3]);   // row 17+4jj
      if (jj != 11) load2(bufA, 2 * jj + 2);  // next pair's A
      fmarow(va.z, vb.z, bufB[0], bufB[1]);   // row 18+4jj   (from B = hc 2jj+1)
      fmarow(va.w, vb.w, bufB[2], bufB[3]);   // row 19+4jj
    }

    // ---- LDS-resident rows 64..65 (row 65 is pad=0 for p<7) ----
    {
      const float ia64 = sin0[64], ib64 = sin1[64];
      const float ia65 = sin0[65], ib65 = sin1[65];
      #pragma unroll
      for (int c = 0; c < 8; ++c) {
        const float wA = wlds[c * kBlk + t_];
        const float wB = wlds[(8 + c) * kBlk + t_];
        acc[c][0] = fmaf(ia64, wA, acc[c][0]);
        acc[c][0] = fmaf(ia65, wB, acc[c][0]);
        acc[c][1] = fmaf(ib64, wA, acc[c][1]);
        acc[c][1] = fmaf(ib65, wB, acc[c][1]);
      }
    }

    // ---- reduce across the 8 k-slices (lanes differing in bits 0..2) ----
    #pragma unroll
    for (int c = 0; c < 8; ++c) {
      #pragma unroll
      for (int b = 0; b < 2; ++b) {
        float v = acc[c][b];
        v = dpp_xor_add<0xB1>(v);      // quad_perm xor1
        v = dpp_xor_add<0x4E>(v);      // quad_perm xor2
        v = swz_add<0x101F>(v);        // xor4
        acc[c][b] = v;
      }
    }

    // ---- select this thread's col (c == p) via cndmask tree ----
    const bool q1 = (t_ & 1), q2 = (t_ & 2), q4 = (t_ & 4);
    float sel0, sel1;
    {
      float a01 = q1 ? acc[1][0] : acc[0][0];
      float a23 = q1 ? acc[3][0] : acc[2][0];
      float a45 = q1 ? acc[5][0] : acc[4][0];
      float a67 = q1 ? acc[7][0] : acc[6][0];
      float a03 = q2 ? a23 : a01;
      float a47 = q2 ? a67 : a45;
      sel0 = q4 ? a47 : a03;
      float b01 = q1 ? acc[1][1] : acc[0][1];
      float b23 = q1 ? acc[3][1] : acc[2][1];
      float b45 = q1 ? acc[5][1] : acc[4][1];
      float b67 = q1 ? acc[7][1] : acc[6][1];
      float b03 = q2 ? b23 : b01;
      float b47 = q2 ? b67 : b45;
      sel1 = q4 ? b47 : b03;
    }
    const float h0 = tanhf(sel0 + b1t);
    const float h1 = tanhf(sel1 + b1t);

    // ---- output head: 64-lane butterfly + cross-wave LDS combine ----
    float p0 = h0 * w2t;
    float p1 = h1 * w2t;
    p0 = dpp_xor_add<0xB1>(p0);  p1 = dpp_xor_add<0xB1>(p1);
    p0 = dpp_xor_add<0x4E>(p0);  p1 = dpp_xor_add<0x4E>(p1);
    p0 = swz_add<0x101F>(p0);    p1 = swz_add<0x101F>(p1);   // xor4
    p0 = swz_add<0x201F>(p0);    p1 = swz_add<0x201F>(p1);   // xor8
    p0 = swz_add<0x401F>(p0);    p1 = swz_add<0x401F>(p1);   // xor16
    p0 += __shfl_xor(p0, 32, 64);
    p1 += __shfl_xor(p1, 32, 64);
    const int wid = t_ >> 6;
    if ((t_ & 63) == 0) { red[0][wid] = p0; red[1][wid] = p1; }
    __syncthreads();  // barrier A: all inp reads done; red populated

    const float d0 = ((red[0][0] + red[0][1]) + (red[0][2] + red[0][3])) +
                     ((red[0][4] + red[0][5]) + (red[0][6] + red[0][7]));
    const float d1 = ((red[1][0] + red[1][1]) + (red[1][2] + red[1][3])) +
                     ((red[1][4] + red[1][5]) + (red[1][6] + red[1][7]));
    const float o0 = d0 + b2v;   // bit-identical in every thread
    const float o1 = d1 + b2v;
    if (t_ == 0) {
      outp[n0 * kL + t] = o0;
      outp[n1 * kL + t] = o1;
    }

    // ---- stage step t+1 ----
    in0[haddr] = h0;
    in1[haddr] = h1;
    if (t + 1 < kL) {
      s0 += xs0 - o0;   // wave-uniform
      s1 += xs1 - o1;
      if (t_ < 8)       in0[t_]     = xnext;
      else if (t_ < 16) in1[t_ - 8] = xnext;
      if (t_ == 16)     in0[8] = s0;
      if (t_ == 17)     in1[8] = s1;
      if (t_ == 0) {
        stor[n0 * kL + t + 1] = s0;
        stor[n1 * kL + t + 1] = s1;
      }
    }
    __syncthreads();  // barrier B
  }
}

extern "C" void kernel_launch(void* const* d_in, const int* in_sizes, int n_in,
                              void* d_out, int out_size, void* d_ws, size_t ws_size,
                              hipStream_t stream) {
  const float* x  = (const float*)d_in[0];
  const float* W1 = (const float*)d_in[1];
  const float* b1 = (const float*)d_in[2];
  const float* W2 = (const float*)d_in[3];
  const float* b2 = (const float*)d_in[4];
  float* out = (float*)d_out;

  dim3 grid(kN / kBpb);   // 128 blocks, 1/CU
  dim3 block(kBlk);
  hipLaunchKernelGGL(resrnn_fwd, grid, block, 0, stream, x, W1, b1, W2, b2, out);
}

// Round 5
// 23494.547 us; speedup vs baseline: 1.5250x; 1.5250x over previous
//
#include <hip/hip_runtime.h>
#include <math.h>

// resRNN fwd: N=256 seqs, L=1024 steps, inp=521 (8 x + 1 storage + 512 hx),
// HID=512, OUT=1, fp32 (no fp32 MFMA on CDNA4).
//
// Round 5 = round 4 with the spill fixed:
//  * __launch_bounds__(512, 1): on this toolchain the 2nd arg empirically acts
//    as min BLOCKS/CU (round 4: arg=2 -> VGPR capped at 128 -> wr[] spilled to
//    scratch -> 15 GB HBM scratch thrash, 36 ms). arg=1 -> 256-VGPR budget.
//  * No private arrays passed by reference / no lambdas: named float4 stream
//    buffers + macros so SROA can keep everything in registers.
// Design: 128 blocks x 512 thr, 2 batch/block. Thread t=(jg=t>>3,p=t&7) owns
// cols [8jg,8jg+8) over slice rows [65p,65p+65]; inp = 8 slices padded to 68
// floats (pads=0 so overlap row contributes 0).
//   slice rows 0..15 : VGPR-resident (32 named float4 = 128 regs)
//   slice rows 16..63: streamed from L2, A/B double-buffered float4s
//   slice rows 64..65: LDS-resident (32 KB)

constexpr int kN   = 256;
constexpr int kL   = 1024;
constexpr int kHid = 512;
constexpr int kBlk = 512;
constexpr int kBpb = 2;
constexpr int PADSL = 68;

template <int CTRL>
__device__ __forceinline__ float dpp_xor_add(float x) {
  int yi = __builtin_amdgcn_update_dpp(0, __float_as_int(x), CTRL, 0xF, 0xF, true);
  return x + __int_as_float(yi);
}
template <int PAT>
__device__ __forceinline__ float swz_add(float x) {
  int yi = __builtin_amdgcn_ds_swizzle(__float_as_int(x), PAT);
  return x + __int_as_float(yi);
}

#define LD4(pp) (*reinterpret_cast<const float4*>(pp))

// acc update: 8 cols x 2 batch, weights as two float4 values
#define FMAROW(ia, ib, w0, w1)                                          \
  acc[0][0] = fmaf((ia), (w0).x, acc[0][0]);                            \
  acc[0][1] = fmaf((ib), (w0).x, acc[0][1]);                            \
  acc[1][0] = fmaf((ia), (w0).y, acc[1][0]);                            \
  acc[1][1] = fmaf((ib), (w0).y, acc[1][1]);                            \
  acc[2][0] = fmaf((ia), (w0).z, acc[2][0]);                            \
  acc[2][1] = fmaf((ib), (w0).z, acc[2][1]);                            \
  acc[3][0] = fmaf((ia), (w0).w, acc[3][0]);                            \
  acc[3][1] = fmaf((ib), (w0).w, acc[3][1]);                            \
  acc[4][0] = fmaf((ia), (w1).x, acc[4][0]);                            \
  acc[4][1] = fmaf((ib), (w1).x, acc[4][1]);                            \
  acc[5][0] = fmaf((ia), (w1).y, acc[5][0]);                            \
  acc[5][1] = fmaf((ib), (w1).y, acc[5][1]);                            \
  acc[6][0] = fmaf((ia), (w1).z, acc[6][0]);                            \
  acc[6][1] = fmaf((ib), (w1).z, acc[6][1]);                            \
  acc[7][0] = fmaf((ia), (w1).w, acc[7][0]);                            \
  acc[7][1] = fmaf((ib), (w1).w, acc[7][1]);

#define LOAD2A(hc) {                                                    \
  const float* b_ = wst + (hc) * 2 * kHid;                              \
  bA0 = LD4(b_);          bA1 = LD4(b_ + 4);                            \
  bA2 = LD4(b_ + kHid);   bA3 = LD4(b_ + kHid + 4); }
#define LOAD2B(hc) {                                                    \
  const float* b_ = wst + (hc) * 2 * kHid;                              \
  bB0 = LD4(b_);          bB1 = LD4(b_ + 4);                            \
  bB2 = LD4(b_ + kHid);   bB3 = LD4(b_ + kHid + 4); }

// resident rows 4g..4g+3 against inp f4 group g; r0..r3 are literal tokens
#define RES_GROUP(g, r0, r1, r2, r3) {                                  \
  const float4 va = in0f4[g];                                           \
  const float4 vb = in1f4[g];                                           \
  FMAROW(va.x, vb.x, wr##r0##a, wr##r0##b)                              \
  FMAROW(va.y, vb.y, wr##r1##a, wr##r1##b)                              \
  FMAROW(va.z, vb.z, wr##r2##a, wr##r2##b)                              \
  FMAROW(va.w, vb.w, wr##r3##a, wr##r3##b) }

// streamed group jj (rows 16+4jj..19+4jj); last==1 on jj=11
#define STREAM_STEP(jj, last) {                                         \
  LOAD2B(2 * (jj) + 1);                                                 \
  const float4 va = in0f4[4 + (jj)];                                    \
  const float4 vb = in1f4[4 + (jj)];                                    \
  FMAROW(va.x, vb.x, bA0, bA1)                                          \
  FMAROW(va.y, vb.y, bA2, bA3)                                          \
  if (!(last)) { LOAD2A(2 * (jj) + 2); }                                \
  FMAROW(va.z, vb.z, bB0, bB1)                                          \
  FMAROW(va.w, vb.w, bB2, bB3) }

__global__ __launch_bounds__(kBlk, 1)
void resrnn_fwd(const float* __restrict__ x, const float* __restrict__ W1,
                const float* __restrict__ b1, const float* __restrict__ W2,
                const float* __restrict__ b2, float* __restrict__ out) {
  __shared__ float wlds[16 * kBlk];                    // slice rows {64,65}, 32 KB
  __shared__ __align__(16) float in0[8 * PADSL];
  __shared__ __align__(16) float in1[8 * PADSL];
  __shared__ float red[2][8];

  const int t_  = threadIdx.x;
  const int p   = t_ & 7;
  const int col0 = t_ & ~7;
  const int kbase = 65 * p;

  const int n0 = blockIdx.x * kBpb;
  const int n1 = n0 + 1;
  const float* __restrict__ x0 = x + (size_t)n0 * kL * 8;
  const float* __restrict__ x1 = x + (size_t)n1 * kL * 8;
  float* const outp = out;
  float* const stor = out + (size_t)kN * kL;

  const float b2v = b2[0];
  const float b1t = b1[t_];
  const float w2t = W2[t_];

  const float* __restrict__ wbase = W1 + (size_t)kbase * kHid + col0;

  // ---- VGPR-resident weights: slice rows 0..15, named vars (no spillable array)
#define DECL_WR(i) \
  float4 wr##i##a = LD4(wbase + i * kHid); \
  float4 wr##i##b = LD4(wbase + i * kHid + 4);
  DECL_WR(0)  DECL_WR(1)  DECL_WR(2)  DECL_WR(3)
  DECL_WR(4)  DECL_WR(5)  DECL_WR(6)  DECL_WR(7)
  DECL_WR(8)  DECL_WR(9)  DECL_WR(10) DECL_WR(11)
  DECL_WR(12) DECL_WR(13) DECL_WR(14) DECL_WR(15)
#undef DECL_WR

  #pragma unroll
  for (int r = 0; r < 2; ++r)
    #pragma unroll
    for (int c = 0; c < 8; ++c)
      wlds[(r * 8 + c) * kBlk + t_] = wbase[(64 + r) * kHid + c];
  const float* __restrict__ wst = wbase + 16 * kHid;   // streamed rows 16..63

  // staging address for hidden row R = 9 + t_ in slice layout
  const int R = 9 + t_;
  const int haddr = (R < 455) ? (R / 65) * PADSL + (R % 65)
                              : 7 * PADSL + (R - 455);

  // ---- init: zero inp (incl pads), stage x_0 / s_0 ----
  in0[t_] = 0.f; in1[t_] = 0.f;
  if (t_ < 8 * PADSL - kBlk) { in0[kBlk + t_] = 0.f; in1[kBlk + t_] = 0.f; }
  __syncthreads();
  float s0 = x0[0];
  float s1 = x1[0];
  if (t_ < 8)       in0[t_]     = x0[t_];
  else if (t_ < 16) in1[t_ - 8] = x1[t_ - 8];
  if (t_ == 16)     in0[8] = s0;
  if (t_ == 17)     in1[8] = s1;
  if (t_ == 0) { stor[n0 * kL] = s0; stor[n1 * kL] = s1; }
  __syncthreads();

  const float4* __restrict__ in0f4 = reinterpret_cast<const float4*>(in0 + p * PADSL);
  const float4* __restrict__ in1f4 = reinterpret_cast<const float4*>(in1 + p * PADSL);
  const float* __restrict__ sin0 = in0 + p * PADSL;
  const float* __restrict__ sin1 = in1 + p * PADSL;

  float acc[8][2];
  float4 bA0, bA1, bA2, bA3, bB0, bB1, bB2, bB3;

  for (int t = 0; t < kL; ++t) {
    // prefetch x(t+1)
    float xs0 = 0.f, xs1 = 0.f, xnext = 0.f;
    if (t + 1 < kL) {
      const float* xr0 = x0 + (size_t)(t + 1) * 8;
      const float* xr1 = x1 + (size_t)(t + 1) * 8;
      xs0 = xr0[0];  xs1 = xr1[0];
      if (t_ < 8)       xnext = xr0[t_];
      else if (t_ < 16) xnext = xr1[t_ - 8];
    }

    #pragma unroll
    for (int c = 0; c < 8; ++c) { acc[c][0] = 0.f; acc[c][1] = 0.f; }

    LOAD2A(0);   // kick stream early

    RES_GROUP(0, 0, 1, 2, 3)
    RES_GROUP(1, 4, 5, 6, 7)
    RES_GROUP(2, 8, 9, 10, 11)
    RES_GROUP(3, 12, 13, 14, 15)

    STREAM_STEP(0, 0)  STREAM_STEP(1, 0)  STREAM_STEP(2, 0)
    STREAM_STEP(3, 0)  STREAM_STEP(4, 0)  STREAM_STEP(5, 0)
    STREAM_STEP(6, 0)  STREAM_STEP(7, 0)  STREAM_STEP(8, 0)
    STREAM_STEP(9, 0)  STREAM_STEP(10, 0) STREAM_STEP(11, 1)

    // LDS-resident slice rows 64..65
    {
      const float ia64 = sin0[64], ib64 = sin1[64];
      const float ia65 = sin0[65], ib65 = sin1[65];
      #pragma unroll
      for (int c = 0; c < 8; ++c) {
        const float wA = wlds[c * kBlk + t_];
        const float wB = wlds[(8 + c) * kBlk + t_];
        acc[c][0] = fmaf(ia64, wA, acc[c][0]);
        acc[c][0] = fmaf(ia65, wB, acc[c][0]);
        acc[c][1] = fmaf(ib64, wA, acc[c][1]);
        acc[c][1] = fmaf(ib65, wB, acc[c][1]);
      }
    }

    // reduce across 8 k-slices (lane bits 0..2)
    #pragma unroll
    for (int c = 0; c < 8; ++c) {
      #pragma unroll
      for (int b = 0; b < 2; ++b) {
        float v = acc[c][b];
        v = dpp_xor_add<0xB1>(v);
        v = dpp_xor_add<0x4E>(v);
        v = swz_add<0x101F>(v);
        acc[c][b] = v;
      }
    }

    // select col c == p via cndmask tree
    const bool q1 = (t_ & 1), q2 = (t_ & 2), q4 = (t_ & 4);
    float sel0, sel1;
    {
      float a01 = q1 ? acc[1][0] : acc[0][0];
      float a23 = q1 ? acc[3][0] : acc[2][0];
      float a45 = q1 ? acc[5][0] : acc[4][0];
      float a67 = q1 ? acc[7][0] : acc[6][0];
      float a03 = q2 ? a23 : a01;
      float a47 = q2 ? a67 : a45;
      sel0 = q4 ? a47 : a03;
      float b01 = q1 ? acc[1][1] : acc[0][1];
      float b23 = q1 ? acc[3][1] : acc[2][1];
      float b45 = q1 ? acc[5][1] : acc[4][1];
      float b67 = q1 ? acc[7][1] : acc[6][1];
      float b03 = q2 ? b23 : b01;
      float b47 = q2 ? b67 : b45;
      sel1 = q4 ? b47 : b03;
    }
    const float h0 = tanhf(sel0 + b1t);
    const float h1 = tanhf(sel1 + b1t);

    // output head: 64-lane butterfly + cross-wave LDS combine
    float p0 = h0 * w2t;
    float p1 = h1 * w2t;
    p0 = dpp_xor_add<0xB1>(p0);  p1 = dpp_xor_add<0xB1>(p1);
    p0 = dpp_xor_add<0x4E>(p0);  p1 = dpp_xor_add<0x4E>(p1);
    p0 = swz_add<0x101F>(p0);    p1 = swz_add<0x101F>(p1);
    p0 = swz_add<0x201F>(p0);    p1 = swz_add<0x201F>(p1);
    p0 = swz_add<0x401F>(p0);    p1 = swz_add<0x401F>(p1);
    p0 += __shfl_xor(p0, 32, 64);
    p1 += __shfl_xor(p1, 32, 64);
    const int wid = t_ >> 6;
    if ((t_ & 63) == 0) { red[0][wid] = p0; red[1][wid] = p1; }
    __syncthreads();  // barrier A

    const float d0 = ((red[0][0] + red[0][1]) + (red[0][2] + red[0][3])) +
                     ((red[0][4] + red[0][5]) + (red[0][6] + red[0][7]));
    const float d1 = ((red[1][0] + red[1][1]) + (red[1][2] + red[1][3])) +
                     ((red[1][4] + red[1][5]) + (red[1][6] + red[1][7]));
    const float o0 = d0 + b2v;
    const float o1 = d1 + b2v;
    if (t_ == 0) {
      outp[n0 * kL + t] = o0;
      outp[n1 * kL + t] = o1;
    }

    // stage step t+1
    in0[haddr] = h0;
    in1[haddr] = h1;
    if (t + 1 < kL) {
      s0 += xs0 - o0;
      s1 += xs1 - o1;
      if (t_ < 8)       in0[t_]     = xnext;
      else if (t_ < 16) in1[t_ - 8] = xnext;
      if (t_ == 16)     in0[8] = s0;
      if (t_ == 17)     in1[8] = s1;
      if (t_ == 0) {
        stor[n0 * kL + t + 1] = s0;
        stor[n1 * kL + t + 1] = s1;
      }
    }
    __syncthreads();  // barrier B
  }
}

extern "C" void kernel_launch(void* const* d_in, const int* in_sizes, int n_in,
                              void* d_out, int out_size, void* d_ws, size_t ws_size,
                              hipStream_t stream) {
  const float* x  = (const float*)d_in[0];
  const float* W1 = (const float*)d_in[1];
  const float* b1 = (const float*)d_in[2];
  const float* W2 = (const float*)d_in[3];
  const float* b2 = (const float*)d_in[4];
  float* out = (float*)d_out;

  dim3 grid(kN / kBpb);   // 128 blocks, 1/CU
  dim3 block(kBlk);
  hipLaunchKernelGGL(resrnn_fwd, grid, block, 0, stream, x, W1, b1, W2, b2, out);
}

// Round 6
// 23202.167 us; speedup vs baseline: 1.5442x; 1.0126x over previous
//
#include <hip/hip_runtime.h>
#include <math.h>

// resRNN fwd: N=256 seqs, L=1024 steps, inp=521 (8 x + 1 storage + 512 hx),
// HID=512, OUT=1, fp32 (no fp32 MFMA on CDNA4).
//
// Round 6: NO VGPR-resident weights. Rounds 4/5 proved this toolchain caps the
// kernel at a 128-VGPR budget regardless of __launch_bounds__ 2nd arg, and
// spills (35->23 ms scratch thrash). So: fit in <128 VGPRs by construction.
//   slice rows 0..63 : streamed from per-XCD L2 (1.02 MB/block/step),
//                      A/B double-buffered float4 pairs (2 pair-loads in
//                      flight/wave -> 64 KB/CU outstanding, saturates the
//                      ~112 B/cyc/CU L2 port share)
//   slice rows 64..65: LDS-resident (32 KB)
// Register demand ~105: acc 16 + bufs 32 + temps/addressing ~55.
//
// Design recap: 128 blocks x 512 thr, 2 batch/block (batch elems independent
// -> zero inter-block comms). Thread t=(jg=t>>3,p=t&7) owns cols [8jg,8jg+8)
// over slice rows [65p,65p+65]; inp = 8 slices padded to 68 floats; slice
// local row 65 stays 0 for p<7 (the overlap row is owned by slice p+1), so
// the extra FMA contributes 0 -> uniform, branch-free.

constexpr int kN   = 256;
constexpr int kL   = 1024;
constexpr int kHid = 512;
constexpr int kBlk = 512;
constexpr int kBpb = 2;
constexpr int PADSL = 68;

template <int CTRL>
__device__ __forceinline__ float dpp_xor_add(float x) {
  int yi = __builtin_amdgcn_update_dpp(0, __float_as_int(x), CTRL, 0xF, 0xF, true);
  return x + __int_as_float(yi);
}
template <int PAT>
__device__ __forceinline__ float swz_add(float x) {
  int yi = __builtin_amdgcn_ds_swizzle(__float_as_int(x), PAT);
  return x + __int_as_float(yi);
}

#define LD4(pp) (*reinterpret_cast<const float4*>(pp))

// acc update: 8 cols x 2 batch, weights as two float4 values
#define FMAROW(ia, ib, w0, w1)                                          \
  acc[0][0] = fmaf((ia), (w0).x, acc[0][0]);                            \
  acc[0][1] = fmaf((ib), (w0).x, acc[0][1]);                            \
  acc[1][0] = fmaf((ia), (w0).y, acc[1][0]);                            \
  acc[1][1] = fmaf((ib), (w0).y, acc[1][1]);                            \
  acc[2][0] = fmaf((ia), (w0).z, acc[2][0]);                            \
  acc[2][1] = fmaf((ib), (w0).z, acc[2][1]);                            \
  acc[3][0] = fmaf((ia), (w0).w, acc[3][0]);                            \
  acc[3][1] = fmaf((ib), (w0).w, acc[3][1]);                            \
  acc[4][0] = fmaf((ia), (w1).x, acc[4][0]);                            \
  acc[4][1] = fmaf((ib), (w1).x, acc[4][1]);                            \
  acc[5][0] = fmaf((ia), (w1).y, acc[5][0]);                            \
  acc[5][1] = fmaf((ib), (w1).y, acc[5][1]);                            \
  acc[6][0] = fmaf((ia), (w1).z, acc[6][0]);                            \
  acc[6][1] = fmaf((ib), (w1).z, acc[6][1]);                            \
  acc[7][0] = fmaf((ia), (w1).w, acc[7][0]);                            \
  acc[7][1] = fmaf((ib), (w1).w, acc[7][1]);

// load slice rows {2hc, 2hc+1} (8 cols each) into buffer A / B
#define LOAD2A(hc) {                                                    \
  const float* b_ = wst + (hc) * 2 * kHid;                              \
  bA0 = LD4(b_);          bA1 = LD4(b_ + 4);                            \
  bA2 = LD4(b_ + kHid);   bA3 = LD4(b_ + kHid + 4); }
#define LOAD2B(hc) {                                                    \
  const float* b_ = wst + (hc) * 2 * kHid;                              \
  bB0 = LD4(b_);          bB1 = LD4(b_ + 4);                            \
  bB2 = LD4(b_ + kHid);   bB3 = LD4(b_ + kHid + 4); }

// streamed group jj: slice rows 4jj..4jj+3 against inp f4 group jj
#define STREAM_STEP(jj, last) {                                         \
  const float4 va = in0f4[jj];                                          \
  const float4 vb = in1f4[jj];                                          \
  FMAROW(va.x, vb.x, bA0, bA1)                                          \
  FMAROW(va.y, vb.y, bA2, bA3)                                          \
  if (!(last)) { LOAD2A(2 * (jj) + 2); }                                \
  FMAROW(va.z, vb.z, bB0, bB1)                                          \
  FMAROW(va.w, vb.w, bB2, bB3)                                          \
  if (!(last)) { LOAD2B(2 * (jj) + 3); } }

__global__ __launch_bounds__(kBlk)
__attribute__((amdgpu_waves_per_eu(1, 2)))
void resrnn_fwd(const float* __restrict__ x, const float* __restrict__ W1,
                const float* __restrict__ b1, const float* __restrict__ W2,
                const float* __restrict__ b2, float* __restrict__ out) {
  __shared__ float wlds[16 * kBlk];                    // slice rows {64,65}, 32 KB
  __shared__ __align__(16) float in0[8 * PADSL];
  __shared__ __align__(16) float in1[8 * PADSL];
  __shared__ float red[2][8];

  const int t_  = threadIdx.x;
  const int p   = t_ & 7;
  const int col0 = t_ & ~7;
  const int kbase = 65 * p;

  const int n0 = blockIdx.x * kBpb;
  const int n1 = n0 + 1;
  const float* __restrict__ x0 = x + (size_t)n0 * kL * 8;
  const float* __restrict__ x1 = x + (size_t)n1 * kL * 8;
  float* const outp = out;
  float* const stor = out + (size_t)kN * kL;

  const float b2v = b2[0];
  const float b1t = b1[t_];
  const float w2t = W2[t_];

  const float* __restrict__ wbase = W1 + (size_t)kbase * kHid + col0;
  const float* __restrict__ wst = wbase;               // stream rows 0..63

  // LDS-resident slice rows 64..65
  #pragma unroll
  for (int r = 0; r < 2; ++r)
    #pragma unroll
    for (int c = 0; c < 8; ++c)
      wlds[(r * 8 + c) * kBlk + t_] = wbase[(64 + r) * kHid + c];

  // staging address for hidden row R = 9 + t_ in slice layout
  const int R = 9 + t_;
  const int haddr = (R < 455) ? (R / 65) * PADSL + (R % 65)
                              : 7 * PADSL + (R - 455);

  // ---- init: zero inp (incl pads), stage x_0 / s_0 ----
  in0[t_] = 0.f; in1[t_] = 0.f;
  if (t_ < 8 * PADSL - kBlk) { in0[kBlk + t_] = 0.f; in1[kBlk + t_] = 0.f; }
  __syncthreads();
  float s0 = x0[0];
  float s1 = x1[0];
  if (t_ < 8)       in0[t_]     = x0[t_];
  else if (t_ < 16) in1[t_ - 8] = x1[t_ - 8];
  if (t_ == 16)     in0[8] = s0;
  if (t_ == 17)     in1[8] = s1;
  if (t_ == 0) { stor[n0 * kL] = s0; stor[n1 * kL] = s1; }
  __syncthreads();

  const float4* __restrict__ in0f4 = reinterpret_cast<const float4*>(in0 + p * PADSL);
  const float4* __restrict__ in1f4 = reinterpret_cast<const float4*>(in1 + p * PADSL);
  const float* __restrict__ sin0 = in0 + p * PADSL;
  const float* __restrict__ sin1 = in1 + p * PADSL;

  float acc[8][2];
  float4 bA0, bA1, bA2, bA3, bB0, bB1, bB2, bB3;

  for (int t = 0; t < kL; ++t) {
    // prefetch x(t+1)
    float xs0 = 0.f, xs1 = 0.f, xnext = 0.f;
    if (t + 1 < kL) {
      const float* xr0 = x0 + (size_t)(t + 1) * 8;
      const float* xr1 = x1 + (size_t)(t + 1) * 8;
      xs0 = xr0[0];  xs1 = xr1[0];
      if (t_ < 8)       xnext = xr0[t_];
      else if (t_ < 16) xnext = xr1[t_ - 8];
    }

    #pragma unroll
    for (int c = 0; c < 8; ++c) { acc[c][0] = 0.f; acc[c][1] = 0.f; }

    // kick the stream, then do LDS-resident work under the first loads
    LOAD2A(0);
    LOAD2B(1);

    // LDS-resident slice rows 64..65 (row 65 is pad=0 for p<7)
    {
      const float ia64 = sin0[64], ib64 = sin1[64];
      const float ia65 = sin0[65], ib65 = sin1[65];
      #pragma unroll
      for (int c = 0; c < 8; ++c) {
        const float wA = wlds[c * kBlk + t_];
        const float wB = wlds[(8 + c) * kBlk + t_];
        acc[c][0] = fmaf(ia64, wA, acc[c][0]);
        acc[c][0] = fmaf(ia65, wB, acc[c][0]);
        acc[c][1] = fmaf(ib64, wA, acc[c][1]);
        acc[c][1] = fmaf(ib65, wB, acc[c][1]);
      }
    }

    // streamed slice rows 0..63: 16 f4-groups
    STREAM_STEP(0, 0)  STREAM_STEP(1, 0)  STREAM_STEP(2, 0)
    STREAM_STEP(3, 0)  STREAM_STEP(4, 0)  STREAM_STEP(5, 0)
    STREAM_STEP(6, 0)  STREAM_STEP(7, 0)  STREAM_STEP(8, 0)
    STREAM_STEP(9, 0)  STREAM_STEP(10, 0) STREAM_STEP(11, 0)
    STREAM_STEP(12, 0) STREAM_STEP(13, 0) STREAM_STEP(14, 0)
    STREAM_STEP(15, 1)

    // reduce across 8 k-slices (lane bits 0..2)
    #pragma unroll
    for (int c = 0; c < 8; ++c) {
      #pragma unroll
      for (int b = 0; b < 2; ++b) {
        float v = acc[c][b];
        v = dpp_xor_add<0xB1>(v);
        v = dpp_xor_add<0x4E>(v);
        v = swz_add<0x101F>(v);
        acc[c][b] = v;
      }
    }

    // select col c == p via cndmask tree
    const bool q1 = (t_ & 1), q2 = (t_ & 2), q4 = (t_ & 4);
    float sel0, sel1;
    {
      float a01 = q1 ? acc[1][0] : acc[0][0];
      float a23 = q1 ? acc[3][0] : acc[2][0];
      float a45 = q1 ? acc[5][0] : acc[4][0];
      float a67 = q1 ? acc[7][0] : acc[6][0];
      float a03 = q2 ? a23 : a01;
      float a47 = q2 ? a67 : a45;
      sel0 = q4 ? a47 : a03;
      float b01 = q1 ? acc[1][1] : acc[0][1];
      float b23 = q1 ? acc[3][1] : acc[2][1];
      float b45 = q1 ? acc[5][1] : acc[4][1];
      float b67 = q1 ? acc[7][1] : acc[6][1];
      float b03 = q2 ? b23 : b01;
      float b47 = q2 ? b67 : b45;
      sel1 = q4 ? b47 : b03;
    }
    const float h0 = tanhf(sel0 + b1t);
    const float h1 = tanhf(sel1 + b1t);

    // output head: 64-lane butterfly + cross-wave LDS combine
    float p0 = h0 * w2t;
    float p1 = h1 * w2t;
    p0 = dpp_xor_add<0xB1>(p0);  p1 = dpp_xor_add<0xB1>(p1);
    p0 = dpp_xor_add<0x4E>(p0);  p1 = dpp_xor_add<0x4E>(p1);
    p0 = swz_add<0x101F>(p0);    p1 = swz_add<0x101F>(p1);
    p0 = swz_add<0x201F>(p0);    p1 = swz_add<0x201F>(p1);
    p0 = swz_add<0x401F>(p0);    p1 = swz_add<0x401F>(p1);
    p0 += __shfl_xor(p0, 32, 64);
    p1 += __shfl_xor(p1, 32, 64);
    const int wid = t_ >> 6;
    if ((t_ & 63) == 0) { red[0][wid] = p0; red[1][wid] = p1; }
    __syncthreads();  // barrier A

    const float d0 = ((red[0][0] + red[0][1]) + (red[0][2] + red[0][3])) +
                     ((red[0][4] + red[0][5]) + (red[0][6] + red[0][7]));
    const float d1 = ((red[1][0] + red[1][1]) + (red[1][2] + red[1][3])) +
                     ((red[1][4] + red[1][5]) + (red[1][6] + red[1][7]));
    const float o0 = d0 + b2v;
    const float o1 = d1 + b2v;
    if (t_ == 0) {
      outp[n0 * kL + t] = o0;
      outp[n1 * kL + t] = o1;
    }

    // stage step t+1
    in0[haddr] = h0;
    in1[haddr] = h1;
    if (t + 1 < kL) {
      s0 += xs0 - o0;
      s1 += xs1 - o1;
      if (t_ < 8)       in0[t_]     = xnext;
      else if (t_ < 16) in1[t_ - 8] = xnext;
      if (t_ == 16)     in0[8] = s0;
      if (t_ == 17)     in1[8] = s1;
      if (t_ == 0) {
        stor[n0 * kL + t + 1] = s0;
        stor[n1 * kL + t + 1] = s1;
      }
    }
    __syncthreads();  // barrier B
  }
}

extern "C" void kernel_launch(void* const* d_in, const int* in_sizes, int n_in,
                              void* d_out, int out_size, void* d_ws, size_t ws_size,
                              hipStream_t stream) {
  const float* x  = (const float*)d_in[0];
  const float* W1 = (const float*)d_in[1];
  const float* b1 = (const float*)d_in[2];
  const float* W2 = (const float*)d_in[3];
  const float* b2 = (const float*)d_in[4];
  float* out = (float*)d_out;

  dim3 grid(kN / kBpb);   // 128 blocks, 1/CU
  dim3 block(kBlk);
  hipLaunchKernelGGL(resrnn_fwd, grid, block, 0, stream, x, W1, b1, W2, b2, out);
}